// Round 6
// baseline (264.998 us; speedup 1.0000x reference)
//
#include <hip/hip_runtime.h>
#include <stdint.h>

// Problem constants: B=16, K=8, C=64, L=2048
#define BB 16
#define KK 8
#define CC 64
#define LL 2048

constexpr int CL = CC * LL;              // 131072 = 2^17 elems per batch
constexpr int NELEM = BB * CL;           // 2,097,152
constexpr int TILE = 256;                // elems per block
constexpr int NBLOCKS = NELEM / TILE;    // 8192 blocks; 512 tiles/batch (exact)
constexpr int NSTREAM = 27;              // x,a,b + 8*(pi,mu,s)

#define SIG_OFF 0.11920292202211755f     // 1 - sigmoid(2) = sigmoid(-2)
#define LOG_EPS -16.11809565095832f      // logf(1e-7)

__device__ __forceinline__ float frcp(float x) { return __builtin_amdgcn_rcpf(x); }

// Async global->LDS DMA, 16 B per lane. No destination VGPR, so the register
// allocator cannot sink/serialize the load burst (R3-R5 failure mode).
// LDS dest = wave-uniform base + lane*16 (contiguous, m104 caveat respected).
__device__ __forceinline__ void load_to_lds16(const float* g, float* l) {
    __builtin_amdgcn_global_load_lds(
        (const __attribute__((address_space(1))) void*)g,
        (__attribute__((address_space(3))) void*)l,
        16, 0, 0);
}

__global__ void init_sldj_kernel(const float* __restrict__ sldj_in,
                                 float* __restrict__ sldj_out) {
    int i = threadIdx.x;
    if (i < BB) sldj_out[i] = sldj_in[i];
}

__global__ __launch_bounds__(256) void coupling_kernel(
    const float* __restrict__ x,
    const float* __restrict__ a,
    const float* __restrict__ bv,
    const float* __restrict__ pi,
    const float* __restrict__ mu,
    const float* __restrict__ s,
    float* __restrict__ out,
    float* __restrict__ sldj_out) {

    __shared__ float lds[NSTREAM * TILE];  // 27 KB: stream s at lds[s*256]

    const int tile = blockIdx.x;
    const int b    = tile >> 9;                    // 512 tiles per batch
    const int base = tile * TILE;                  // global elem base (= b*CL + rem)
    const int rem  = base & (CL - 1);
    const int kb0  = (b << 20) + rem;              // b*K*CL + within-batch offset

    const int lane = threadIdx.x & 63;
    const int wv   = threadIdx.x >> 6;

    // ---- Phase 1: stage all 27 streams via LDS-DMA (1 instr = whole tile) ----
    // stream ids: 0:x 1:a 2:b | 3..10: pi_k | 11..18: mu_k | 19..26: s_k
    for (int sidx = wv; sidx < NSTREAM; sidx += 4) {
        const float* gp;
        if (sidx == 0)       gp = x  + base;
        else if (sidx == 1)  gp = a  + base;
        else if (sidx == 2)  gp = bv + base;
        else if (sidx < 11)  gp = pi + kb0 + (sidx - 3)  * CL;
        else if (sidx < 19)  gp = mu + kb0 + (sidx - 11) * CL;
        else                 gp = s  + kb0 + (sidx - 19) * CL;
        load_to_lds16(gp + lane * 4, &lds[sidx * TILE + lane * 4]);
    }
    __syncthreads();  // vmcnt(0) drain + barrier: all DMAs visible to all waves

    // ---- Phase 2: linear-domain mixture math ----
    const int t  = threadIdx.x;           // element within tile
    const float xe = lds[0 * TILE + t];
    const float ae = lds[1 * TILE + t];
    const float be = lds[2 * TILE + t];

    //   Spi = sum_k e^{pi_k}
    //   Nc  = sum_k e^{pi_k} * sigmoid(z_k)            -> u   = Nc/Spi
    //   N1  = sum_k e^{pi_k} * (1 - sigmoid(z_k))      -> 1-u = N1/Spi
    //   Np  = sum_k e^{pi_k} * e^{-s_k} * sig*(1-sig)  -> pdf = Np/Spi
    float Spi = 0.f, Nc = 0.f, N1 = 0.f, Np = 0.f;

#pragma unroll
    for (int k = 0; k < KK; ++k) {
        const float p  = lds[(3 + k)  * TILE + t];
        const float m  = lds[(11 + k) * TILE + t];
        const float sk = lds[(19 + k) * TILE + t];

        const float invstd = __expf(-sk);
        const float z      = (xe - m) * invstd;

        // stable sigmoid via tt = e^{-|z|}
        const float tt = __expf(-fabsf(z));
        const float r  = frcp(1.f + tt);
        const float tr = tt * r;
        const float sig  = (z >= 0.f) ? r  : tr;
        const float osig = (z >= 0.f) ? tr : r;

        const float ek = __expf(p);
        Spi += ek;
        Nc  += ek * sig;
        N1  += ek * osig;
        Np  += ek * invstd * sig * osig;
    }

    const float lSpi = __logf(Spi);
    const float lu   = fmaxf(__logf(Nc) - lSpi, LOG_EPS);
    const float lomu = fmaxf(__logf(N1) - lSpi, LOG_EPS);
    const float y        = lu - lomu;     // logit(u)
    const float ldj_term = -lu - lomu;
    const float log_pdf  = __logf(Np) - lSpi;

    // scale = sigmoid(a+2) + sigmoid(-2)
    const float av = ae + 2.f;
    const float t2 = __expf(-fabsf(av));
    const float r2 = frcp(1.f + t2);
    const float sc = ((av >= 0.f) ? r2 : t2 * r2) + SIG_OFF;

    out[base + t] = (y + be) * sc;

    float contrib = log_pdf + ldj_term + __logf(sc);

    // ---- block reduction, one atomicAdd per block (block within batch b) ----
#pragma unroll
    for (int off = 32; off > 0; off >>= 1)
        contrib += __shfl_down(contrib, off, 64);

    __shared__ float wsum[4];
    if (lane == 0) wsum[wv] = contrib;
    __syncthreads();
    if (threadIdx.x == 0) {
        atomicAdd(&sldj_out[b], wsum[0] + wsum[1] + wsum[2] + wsum[3]);
    }
}

extern "C" void kernel_launch(void* const* d_in, const int* in_sizes, int n_in,
                              void* d_out, int out_size, void* d_ws, size_t ws_size,
                              hipStream_t stream) {
    const float* x    = (const float*)d_in[0];
    const float* a    = (const float*)d_in[1];
    const float* bv   = (const float*)d_in[2];
    const float* pi   = (const float*)d_in[3];
    const float* mu   = (const float*)d_in[4];
    const float* s    = (const float*)d_in[5];
    const float* sldj = (const float*)d_in[6];

    float* out      = (float*)d_out;
    float* sldj_out = out + (size_t)NELEM;  // outputs concat: out, then sldj

    init_sldj_kernel<<<1, 64, 0, stream>>>(sldj, sldj_out);
    coupling_kernel<<<NBLOCKS, 256, 0, stream>>>(x, a, bv, pi, mu, s, out, sldj_out);
}

// Round 7
// 227.963 us; speedup vs baseline: 1.1625x; 1.1625x over previous
//
#include <hip/hip_runtime.h>

// Problem constants: B=16, K=8, C=64, L=2048
#define BB 16
#define KK 8
#define CC 64
#define LL 2048

constexpr int CL = CC * LL;               // 131072 elems per batch
constexpr int NELEM = BB * CL;            // 2,097,152
constexpr int TILE = 2048;                // elems per block (8 KB/stream runs)
constexpr int NBLOCKS = NELEM / TILE;     // 1024 blocks; 64 blocks/batch (exact)
constexpr int TPB = 256;

#define SIG_OFF 0.11920292202211755f      // 1 - sigmoid(2) = sigmoid(-2)
#define LOG_EPS -16.11809565095832f       // logf(1e-7)

__device__ __forceinline__ float frcp(float x) { return __builtin_amdgcn_rcpf(x); }

// Async global->LDS DMA, 16 B/lane. LDS dest = uniform base + lane*16.
__device__ __forceinline__ void load_to_lds16(const float* g, float* l) {
    __builtin_amdgcn_global_load_lds(
        (const __attribute__((address_space(1))) void*)g,
        (__attribute__((address_space(3))) void*)l,
        16, 0, 0);
}

__global__ void init_sldj_kernel(const float* __restrict__ sldj_in,
                                 float* __restrict__ sldj_out) {
    int i = threadIdx.x;
    if (i < BB) sldj_out[i] = sldj_in[i];
}

__global__ __launch_bounds__(256) void coupling_kernel(
    const float* __restrict__ x,
    const float* __restrict__ a,
    const float* __restrict__ bv,
    const float* __restrict__ pi,
    const float* __restrict__ mu,
    const float* __restrict__ s,
    float* __restrict__ out,
    float* __restrict__ sldj_out) {

    __shared__ float xab[3 * TILE];       // 24 KB: x | a | b
    __shared__ float kbuf[2][3 * TILE];   // 2 x 24 KB: pi | mu | s for one k

    const int blk  = blockIdx.x;
    const int b    = blk >> 6;            // 64 blocks per batch
    const int base = blk * TILE;          // global element base (= b*CL + rem)
    const int rem  = base & (CL - 1);
    const int kb0  = (b << 20) + rem;     // b*K*CL + within-batch offset

    const int tid  = threadIdx.x;
    const int lane = tid & 63;
    const int wv   = tid >> 6;
    const int l4   = lane * 4;            // float offset; byte offset = lane*16

    // ---- Stage x,a,b: 3 streams x 8 KB contiguous (24 DMA instrs, 6/wave) ----
#pragma unroll
    for (int j = 0; j < 6; ++j) {
        const int i  = wv * 6 + j;        // 0..23
        const int st = i >> 3;            // stream 0..2
        const int ch = i & 7;             // 1 KB chunk 0..7
        const float* gp = (st == 0 ? x : st == 1 ? a : bv) + base + ch * 256 + l4;
        load_to_lds16(gp, &xab[st * TILE + ch * 256 + l4]);
    }
    // ---- Stage k=0 chunk: pi,mu,s x 8 KB ----
#pragma unroll
    for (int j = 0; j < 6; ++j) {
        const int i  = wv * 6 + j;
        const int st = i >> 3;
        const int ch = i & 7;
        const float* gp = (st == 0 ? pi : st == 1 ? mu : s) + kb0 + ch * 256 + l4;
        load_to_lds16(gp, &kbuf[0][st * TILE + ch * 256 + l4]);
    }
    __syncthreads();  // drain all DMA issued so far

    // Each thread owns 8 elems: group g in {0,1} -> elems g*1024 + 4*tid .. +3
    float4 x4[2];
    x4[0] = *(const float4*)&xab[0 * TILE + 4 * tid];
    x4[1] = *(const float4*)&xab[0 * TILE + 1024 + 4 * tid];

    float Spi[8] = {0,0,0,0,0,0,0,0};
    float Nc [8] = {0,0,0,0,0,0,0,0};
    float N1 [8] = {0,0,0,0,0,0,0,0};
    float Np [8] = {0,0,0,0,0,0,0,0};

    for (int k = 0; k < KK; ++k) {
        const int cur = k & 1;
        // Software pipeline: issue DMA for k+1 BEFORE computing k.
        if (k + 1 < KK) {
#pragma unroll
            for (int j = 0; j < 6; ++j) {
                const int i  = wv * 6 + j;
                const int st = i >> 3;
                const int ch = i & 7;
                const float* gp = (st == 0 ? pi : st == 1 ? mu : s)
                                  + kb0 + (k + 1) * CL + ch * 256 + l4;
                load_to_lds16(gp, &kbuf[1 - cur][st * TILE + ch * 256 + l4]);
            }
        }
        // Compute k from kbuf[cur] (overlaps the in-flight DMA above)
#pragma unroll
        for (int g = 0; g < 2; ++g) {
            const float4 p4 = *(const float4*)&kbuf[cur][0 * TILE + g * 1024 + 4 * tid];
            const float4 m4 = *(const float4*)&kbuf[cur][1 * TILE + g * 1024 + 4 * tid];
            const float4 s4 = *(const float4*)&kbuf[cur][2 * TILE + g * 1024 + 4 * tid];
            const float xs[4] = {g ? x4[1].x : x4[0].x, g ? x4[1].y : x4[0].y,
                                 g ? x4[1].z : x4[0].z, g ? x4[1].w : x4[0].w};
            const float ps[4] = {p4.x, p4.y, p4.z, p4.w};
            const float ms[4] = {m4.x, m4.y, m4.z, m4.w};
            const float ss[4] = {s4.x, s4.y, s4.z, s4.w};
#pragma unroll
            for (int e = 0; e < 4; ++e) {
                const int ei = g * 4 + e;
                const float invstd = __expf(-ss[e]);
                const float z      = (xs[e] - ms[e]) * invstd;
                const float tt = __expf(-fabsf(z));
                const float r  = frcp(1.f + tt);
                const float tr = tt * r;
                const float sig  = (z >= 0.f) ? r  : tr;
                const float osig = (z >= 0.f) ? tr : r;
                const float ek = __expf(ps[e]);
                Spi[ei] += ek;
                Nc [ei] += ek * sig;
                N1 [ei] += ek * osig;
                Np [ei] += ek * invstd * sig * osig;
            }
        }
        __syncthreads();  // drains DMA(k+1); also guards kbuf reuse
    }

    // ---- Epilogue: finish per-element math, store, reduce sldj ----
    float contrib = 0.f;
#pragma unroll
    for (int g = 0; g < 2; ++g) {
        const float4 a4 = *(const float4*)&xab[1 * TILE + g * 1024 + 4 * tid];
        const float4 b4 = *(const float4*)&xab[2 * TILE + g * 1024 + 4 * tid];
        const float as[4] = {a4.x, a4.y, a4.z, a4.w};
        const float bs[4] = {b4.x, b4.y, b4.z, b4.w};
        float4 o4;
        float* op = (float*)&o4;
#pragma unroll
        for (int e = 0; e < 4; ++e) {
            const int ei = g * 4 + e;
            const float lSpi = __logf(Spi[ei]);
            const float lu   = fmaxf(__logf(Nc[ei]) - lSpi, LOG_EPS);
            const float lomu = fmaxf(__logf(N1[ei]) - lSpi, LOG_EPS);
            const float y        = lu - lomu;      // logit(u)
            const float ldj_term = -lu - lomu;
            const float log_pdf  = __logf(Np[ei]) - lSpi;

            const float av = as[e] + 2.f;
            const float t2 = __expf(-fabsf(av));
            const float r2 = frcp(1.f + t2);
            const float sc = ((av >= 0.f) ? r2 : t2 * r2) + SIG_OFF;

            op[e] = (y + bs[e]) * sc;
            contrib += log_pdf + ldj_term + __logf(sc);
        }
        *(float4*)(out + base + g * 1024 + 4 * tid) = o4;
    }

    // block reduction, one atomicAdd per block (block within batch b)
#pragma unroll
    for (int off = 32; off > 0; off >>= 1)
        contrib += __shfl_down(contrib, off, 64);

    __shared__ float wsum[4];
    if (lane == 0) wsum[wv] = contrib;
    __syncthreads();
    if (tid == 0) {
        atomicAdd(&sldj_out[b], wsum[0] + wsum[1] + wsum[2] + wsum[3]);
    }
}

extern "C" void kernel_launch(void* const* d_in, const int* in_sizes, int n_in,
                              void* d_out, int out_size, void* d_ws, size_t ws_size,
                              hipStream_t stream) {
    const float* x    = (const float*)d_in[0];
    const float* a    = (const float*)d_in[1];
    const float* bv   = (const float*)d_in[2];
    const float* pi   = (const float*)d_in[3];
    const float* mu   = (const float*)d_in[4];
    const float* s    = (const float*)d_in[5];
    const float* sldj = (const float*)d_in[6];

    float* out      = (float*)d_out;
    float* sldj_out = out + (size_t)NELEM;  // outputs concat: out, then sldj

    init_sldj_kernel<<<1, 64, 0, stream>>>(sldj, sldj_out);
    coupling_kernel<<<NBLOCKS, TPB, 0, stream>>>(x, a, bv, pi, mu, s, out, sldj_out);
}